// Round 1
// 214.490 us; speedup vs baseline: 1.0062x; 1.0062x over previous
//
#include <hip/hip_runtime.h>

// Flash-attention fwd, B=2,S=2048,H=16,D=128, logits = QK^T / D.
// Round 8: LDS-pressure round. R7 counters (MfmaUtil 34 / VALU 29 / HBM 21%)
// implicated the unreported LDS pipe (~36 b128 reads per 32 MFMA ~ 75% busy).
// Changes:
//  (1) Each wave owns 64 q rows (2x 32x32 tiles): every K/V b128 read feeds
//      TWO MFMAs -> LDS reads per MFMA 1.125 -> 0.5. BQ=256, grid 8x32=256.
//  (2) P stays in registers: S^T lane layout -> PV A-frag via bf16 pack +
//      v_permlane32_swap_b32 (lane l <-> l+32). Pt LDS buffer deleted.
//  (3) log2(e)/D folded into Q's fp32->bf16 convert pass.
// 1 block/CU, 4 waves (1/SIMD): VGPR budget ~450 ok via __launch_bounds__(256,1).
// LDS = 71,680 B (2x K 17,408 + 2x V 18,432).

#define SEQ   2048
#define NHEAD 16
#define DH    128
#define NB    2
#define BQ    256
#define BK    64
#define NTHR  256
#define KSTR  136   // ushorts; 272B row
#define VSTR  72    // ushorts; 144B row
#define NKV   (SEQ / BK)
#define NELEM (NB * SEQ * NHEAD * DH)

typedef __attribute__((ext_vector_type(8)))  short bf16x8;
typedef __attribute__((ext_vector_type(16))) float f32x16;
typedef __attribute__((ext_vector_type(4)))  unsigned int u32x4;

__device__ __forceinline__ unsigned short f2bf(float x) {
    unsigned int u = __builtin_bit_cast(unsigned int, x);
    u += 0x7fffu + ((u >> 16) & 1u);
    return (unsigned short)(u >> 16);
}

// two f32 -> packed bf16 dword (truncate; same P rounding as R7)
__device__ __forceinline__ unsigned int pk2bf(float lo, float hi) {
    return (__builtin_bit_cast(unsigned int, hi) & 0xffff0000u)
         | (__builtin_bit_cast(unsigned int, lo) >> 16);
}

// exchange: a.hi32lanes <-> b.lo32lanes  (v_permlane32_swap_b32)
__device__ __forceinline__ void pl32(unsigned int& a, unsigned int& b) {
    asm("v_permlane32_swap_b32 %0, %1" : "+v"(a), "+v"(b));
}

// ---- pass 1: fp32 -> bf16 (RNE); Q additionally scaled by log2(e)/D
__global__ __launch_bounds__(256) void cvt_bf16(
    const float* __restrict__ q, const float* __restrict__ k,
    const float* __restrict__ v, unsigned short* __restrict__ dst)
{
    const int y = blockIdx.y;
    const float* s = (y == 0) ? q : (y == 1) ? k : v;
    const float scl = (y == 0) ? (1.44269504088896340736f / 128.0f) : 1.0f;
    unsigned short* d = dst + (size_t)y * NELEM;
    const int i = blockIdx.x * 256 + threadIdx.x;
    const float4 x = ((const float4*)s)[i];
    ushort4 o;
    o.x = f2bf(x.x * scl); o.y = f2bf(x.y * scl);
    o.z = f2bf(x.z * scl); o.w = f2bf(x.w * scl);
    ((ushort4*)d)[i] = o;
}

// ---- pass 2: attention
__global__ __launch_bounds__(NTHR, 1) void attn_fwd(
    const unsigned short* __restrict__ Qb,
    const unsigned short* __restrict__ Kb,
    const unsigned short* __restrict__ Vb,
    float* __restrict__ O)
{
    __shared__ unsigned short Kl[2][BK * KSTR];   // 2 x 17,408 B
    __shared__ unsigned short Vl[2][DH * VSTR];   // 2 x 18,432 B  [d][k]

    const int tid  = threadIdx.x;
    const int wave = tid >> 6;
    const int lane = tid & 63;
    const int hx   = lane >> 5;   // 0/1
    const int l32  = lane & 31;

    const int b  = blockIdx.y >> 4;
    const int h  = blockIdx.y & 15;
    const int q0 = blockIdx.x * BQ;

    const size_t rs = (size_t)NHEAD * DH;   // 2048 elems between seq rows
    const unsigned short* qb = Qb + (size_t)b * SEQ * rs + (size_t)h * DH;
    const unsigned short* kb = Kb + (size_t)b * SEQ * rs + (size_t)h * DH;
    const unsigned short* vb = Vb + (size_t)b * SEQ * rs + (size_t)h * DH;

    // ---- Q as B-operand frags for 2 q-subtiles: B[k=d][n=q], n=l32,
    // k=(lane>>5)*8+j (+c*16). Q is pre-scaled by log2(e)/D.
    bf16x8 qf[2][8];
    #pragma unroll
    for (int qt = 0; qt < 2; ++qt) {
        const unsigned short* qp =
            qb + (size_t)(q0 + wave * 64 + qt * 32 + l32) * rs + hx * 8;
        #pragma unroll
        for (int c = 0; c < 8; ++c)
            qf[qt][c] = *(const bf16x8*)(qp + c * 16);
    }

    // ---- staging maps (unchanged from R7; NTHR=256)
    int kgo[4], kls[4];   // K: 1024 16B-chunks: key=cidx>>4, cc=cidx&15
    #pragma unroll
    for (int p = 0; p < 4; ++p) {
        const int cidx = (wave * 4 + p) * 64 + lane;
        const int key  = cidx >> 4;
        const int cc   = cidx & 15;
        kgo[p] = key * (int)rs + cc * 8;
        kls[p] = key * KSTR + cc * 8;
    }
    const int kp  = tid & 31;   // V: key-pair index
    const int dcv = tid >> 5;   // V: d-chunk 0..7 (+8 on p=1)

    f32x16 o4[2][4];
    #pragma unroll
    for (int qt = 0; qt < 2; ++qt)
        #pragma unroll
        for (int t = 0; t < 4; ++t)
            #pragma unroll
            for (int r = 0; r < 16; ++r) o4[qt][t][r] = 0.f;
    float lsum[2] = {0.f, 0.f};

    bf16x8 kr[4], vr[4];

    // prologue: stage tile 0 into buffer 0
    {
        #pragma unroll
        for (int p = 0; p < 4; ++p) kr[p] = *(const bf16x8*)(kb + kgo[p]);
        #pragma unroll
        for (int p = 0; p < 2; ++p) {
            const unsigned short* src = vb + (size_t)(2 * kp) * rs + (dcv + p * 8) * 8;
            vr[p * 2]     = *(const bf16x8*)src;
            vr[p * 2 + 1] = *(const bf16x8*)(src + rs);
        }
        #pragma unroll
        for (int p = 0; p < 4; ++p) *(bf16x8*)&Kl[0][kls[p]] = kr[p];
        unsigned int* vw = (unsigned int*)&Vl[0][0];
        #pragma unroll
        for (int p = 0; p < 2; ++p)
            #pragma unroll
            for (int j = 0; j < 8; ++j) {
                const unsigned int pr = ((unsigned int)(unsigned short)vr[p * 2][j])
                                      | (((unsigned int)(unsigned short)vr[p * 2 + 1][j]) << 16);
                vw[((dcv + p * 8) * 8 + j) * (VSTR / 2) + kp] = pr;
            }
    }
    __syncthreads();

    for (int kv = 0; kv < NKV; ++kv) {
        const int cur = kv & 1;
        const int k0n = ((kv + 1) & (NKV - 1)) * BK;

        // ---- issue next tile's global loads (consumed after compute)
        #pragma unroll
        for (int p = 0; p < 4; ++p) kr[p] = *(const bf16x8*)(kb + (size_t)k0n * rs + kgo[p]);
        #pragma unroll
        for (int p = 0; p < 2; ++p) {
            const unsigned short* src = vb + (size_t)(k0n + 2 * kp) * rs + (dcv + p * 8) * 8;
            vr[p * 2]     = *(const bf16x8*)src;
            vr[p * 2 + 1] = *(const bf16x8*)(src + rs);
        }

        const unsigned short* Kc = &Kl[cur][0];
        const unsigned short* Vc = &Vl[cur][0];

        #pragma unroll
        for (int kt = 0; kt < 2; ++kt) {
            // ---- S^T(32 keys x 32 q) = K * Q^T, for both q-subtiles;
            // each kf read feeds 2 MFMAs.
            f32x16 s[2];
            #pragma unroll
            for (int r = 0; r < 16; ++r) { s[0][r] = 0.f; s[1][r] = 0.f; }
            #pragma unroll
            for (int c = 0; c < 8; ++c) {
                bf16x8 kf = *(const bf16x8*)&Kc[(kt * 32 + l32) * KSTR + c * 16 + hx * 8];
                s[0] = __builtin_amdgcn_mfma_f32_32x32x16_bf16(kf, qf[0][c], s[0], 0, 0, 0);
                s[1] = __builtin_amdgcn_mfma_f32_32x32x16_bf16(kf, qf[1][c], s[1], 0, 0, 0);
            }

            // ---- exp2 (arg pre-scaled via Q) + pack to bf16 dwords.
            // lane holds P[q=l32][key=(r&3)+8*(r>>2)+4*hx]; word w[g][p] =
            // keys (8g+4hx+2p, +1).
            unsigned int w[2][4][2];
            #pragma unroll
            for (int qt = 0; qt < 2; ++qt)
                #pragma unroll
                for (int g = 0; g < 4; ++g) {
                    const float e0 = __builtin_amdgcn_exp2f(s[qt][g * 4 + 0]);
                    const float e1 = __builtin_amdgcn_exp2f(s[qt][g * 4 + 1]);
                    const float e2 = __builtin_amdgcn_exp2f(s[qt][g * 4 + 2]);
                    const float e3 = __builtin_amdgcn_exp2f(s[qt][g * 4 + 3]);
                    lsum[qt] += (e0 + e1) + (e2 + e3);
                    w[qt][g][0] = pk2bf(e0, e1);
                    w[qt][g][1] = pk2bf(e2, e3);
                }

            // ---- lane l <-> l+32 half-exchange: after swap of (g,g+1),
            // [a0,a1,b0,b1] is the A-frag bf16x8 with keys 8hx..8hx+7 (+16ks).
            #pragma unroll
            for (int qt = 0; qt < 2; ++qt)
                #pragma unroll
                for (int ks = 0; ks < 2; ++ks) {
                    pl32(w[qt][2 * ks][0], w[qt][2 * ks + 1][0]);
                    pl32(w[qt][2 * ks][1], w[qt][2 * ks + 1][1]);
                }
            bf16x8 pf[2][2];
            #pragma unroll
            for (int qt = 0; qt < 2; ++qt)
                #pragma unroll
                for (int ks = 0; ks < 2; ++ks) {
                    u32x4 t;
                    t.x = w[qt][2 * ks][0];
                    t.y = w[qt][2 * ks][1];
                    t.z = w[qt][2 * ks + 1][0];
                    t.w = w[qt][2 * ks + 1][1];
                    pf[qt][ks] = __builtin_bit_cast(bf16x8, t);
                }

            // ---- O += P V; each vf read feeds 2 MFMAs (both q-subtiles)
            #pragma unroll
            for (int ks = 0; ks < 2; ++ks)
                #pragma unroll
                for (int dt = 0; dt < 4; ++dt) {
                    bf16x8 vf = *(const bf16x8*)&Vc[(dt * 32 + l32) * VSTR
                                                    + kt * 32 + ks * 16 + hx * 8];
                    o4[0][dt] = __builtin_amdgcn_mfma_f32_32x32x16_bf16(pf[0][ks], vf, o4[0][dt], 0, 0, 0);
                    o4[1][dt] = __builtin_amdgcn_mfma_f32_32x32x16_bf16(pf[1][ks], vf, o4[1][dt], 0, 0, 0);
                }
        }

        // ---- write staged next tile into the other buffer
        const int nxt = cur ^ 1;
        #pragma unroll
        for (int p = 0; p < 4; ++p) *(bf16x8*)&Kl[nxt][kls[p]] = kr[p];
        {
            unsigned int* vw = (unsigned int*)&Vl[nxt][0];
            #pragma unroll
            for (int p = 0; p < 2; ++p)
                #pragma unroll
                for (int j = 0; j < 8; ++j) {
                    const unsigned int pr = ((unsigned int)(unsigned short)vr[p * 2][j])
                                          | (((unsigned int)(unsigned short)vr[p * 2 + 1][j]) << 16);
                    vw[((dcv + p * 8) * 8 + j) * (VSTR / 2) + kp] = pr;
                }
        }
        __syncthreads();
    }

    // ---- epilogue: L per q, then normalize + store (coalesced 128B runs)
    #pragma unroll
    for (int qt = 0; qt < 2; ++qt) {
        float ls = lsum[qt];
        ls += __shfl_xor(ls, 32, 64);
        const float inv = 1.0f / ls;     // valid for q = l32 (both halves)
        float iv[16];
        #pragma unroll
        for (int r = 0; r < 16; ++r)
            iv[r] = __shfl(inv, (r & 3) + 8 * (r >> 2) + 4 * hx, 64);

        #pragma unroll
        for (int dt = 0; dt < 4; ++dt)
            #pragma unroll
            for (int r = 0; r < 16; ++r) {
                const int ql = (r & 3) + 8 * (r >> 2) + 4 * hx;
                const int qg = q0 + wave * 64 + qt * 32 + ql;
                O[(size_t)(b * SEQ + qg) * rs + (size_t)h * DH + dt * 32 + l32]
                    = o4[qt][dt][r] * iv[r];
            }
    }
}

extern "C" void kernel_launch(void* const* d_in, const int* in_sizes, int n_in,
                              void* d_out, int out_size, void* d_ws, size_t ws_size,
                              hipStream_t stream) {
    const float* q = (const float*)d_in[0];
    const float* k = (const float*)d_in[1];
    const float* v = (const float*)d_in[2];
    float* o = (float*)d_out;
    unsigned short* wsb = (unsigned short*)d_ws;

    cvt_bf16<<<dim3(NELEM / 1024, 3), 256, 0, stream>>>(q, k, v, wsb);
    attn_fwd<<<dim3(SEQ / BQ, NB * NHEAD), dim3(NTHR), 0, stream>>>(
        wsb, wsb + NELEM, wsb + 2 * (size_t)NELEM, o);
}